// Round 5
// baseline (185.491 us; speedup 1.0000x reference)
//
#include <hip/hip_runtime.h>
#include <stdint.h>

#define BB 16
#define NN 2048
#define CC 80
#define CONF_THRV 0.5f
#define NMS_THRV 0.5f

// ============ K1: classify + key-build + bitonic sort + gather =============
// One block per batch, 512 threads (8 waves), 4 elements/thread.
// conf/cls/keys live in LDS only — no global round-trip, no k_classify launch.
__global__ __launch_bounds__(512) void k_sort_all(
    const float4* __restrict__ boxes,          // [B][N] cx,cy,w,h
    const float* __restrict__ obj,             // [B][N]
    const float* __restrict__ logits,          // [B][N][CC]
    float4* __restrict__ sxyxy,
    float* __restrict__ sarea,
    float* __restrict__ sobj,
    float* __restrict__ sconf,
    int* __restrict__ scls,
    int* __restrict__ nvalid) {
  __shared__ unsigned long long sk[NN];   // 16 KB sort keys
  __shared__ float lconf[NN];             // 8 KB
  __shared__ int lcls[NN];                // 8 KB
  __shared__ int cnt;
  int b = blockIdx.x;
  int t = threadIdx.x;
  if (t == 0) cnt = 0;
  size_t base = (size_t)b * NN;

  // ---- stage A: per-anchor class argmax + sort key, straight into LDS ----
  #pragma unroll
  for (int rep = 0; rep < 4; ++rep) {
    int a = t + rep * 512;
    const float4* lp = (const float4*)(logits + (base + a) * CC);
    float best = -INFINITY;
    int bi = 0;
    #pragma unroll
    for (int q = 0; q < CC / 4; ++q) {
      float4 v = lp[q];
      if (v.x > best) { best = v.x; bi = 4 * q + 0; }
      if (v.y > best) { best = v.y; bi = 4 * q + 1; }
      if (v.z > best) { best = v.z; bi = 4 * q + 2; }
      if (v.w > best) { best = v.w; bi = 4 * q + 3; }
    }
    lconf[a] = best;
    lcls[a] = bi;
    float o = obj[base + a];
    float s = (o > CONF_THRV) ? o : -INFINITY;
    unsigned u = __float_as_uint(s);
    u = (u & 0x80000000u) ? ~u : (u | 0x80000000u);
    // descending key: score major, smaller original index first on ties
    sk[a] = ((unsigned long long)u << 32) |
            (unsigned long long)(0xFFFFFFFFu - (unsigned)a);
  }
  __syncthreads();

  // ---- stage B: bitonic sort, descending (identical network to r4) ----
  for (unsigned k = 2; k <= NN; k <<= 1) {
    for (unsigned j = k >> 1; j > 0; j >>= 1) {
      #pragma unroll
      for (int rep = 0; rep < 4; ++rep) {
        unsigned e = (unsigned)t + (unsigned)rep * 512u;
        unsigned ixj = e ^ j;
        if (ixj > e) {
          unsigned long long a = sk[e], c = sk[ixj];
          bool up = ((e & k) == 0);
          bool doswap = up ? (a < c) : (a > c);
          if (doswap) { sk[e] = c; sk[ixj] = a; }
        }
      }
      __syncthreads();
    }
  }

  // ---- stage C: gather sorted data to global ----
  int localvalid = 0;
  #pragma unroll
  for (int rep = 0; rep < 4; ++rep) {
    int e = t + rep * 512;
    unsigned long long key = sk[e];
    unsigned id = 0xFFFFFFFFu - (unsigned)(key & 0xFFFFFFFFull);
    float4 bx = boxes[base + id];
    float hw = bx.z / 2.0f, hh = bx.w / 2.0f;
    float x1 = bx.x - hw, y1 = bx.y - hh;
    float x2 = bx.x + hw, y2 = bx.y + hh;
    float o = obj[base + id];
    sxyxy[base + e] = make_float4(x1, y1, x2, y2);
    sarea[base + e] = __fmul_rn(x2 - x1 + 1.0f, y2 - y1 + 1.0f);
    sobj[base + e] = o;
    sconf[base + e] = lconf[id];
    scls[base + e] = lcls[id];
    if (o > CONF_THRV) localvalid++;
  }
  atomicAdd(&cnt, localvalid);
  __syncthreads();
  if (t == 0) nvalid[b] = cnt;
}

// ============ K2: suppression masks, TRANSPOSED layout (unchanged) =========
// masksT[(b*64 + w)*NN + i] = bits for rows j in [32w,32w+32) suppressed by i.
// All i<2048 rows written (zeros where inactive) so the scan needs no guards.
__global__ void k_masks(const float4* __restrict__ sxyxy,
                        const float* __restrict__ sarea,
                        const int* __restrict__ scls,
                        const int* __restrict__ nvalid,
                        uint32_t* __restrict__ masksT) {
  int b = blockIdx.y;
  int pair = blockIdx.x * blockDim.x + threadIdx.x;  // [0, NN*64)
  int i = pair & (NN - 1);
  int w = pair >> 11;
  int nv = nvalid[b];
  size_t base = (size_t)b * NN;
  uint32_t bits = 0;
  int j0 = w * 32;
  int jend = min(j0 + 32, nv);
  int jstart = max(j0, i + 1);
  if (i < nv && jstart < jend) {
    float4 bi = sxyxy[base + i];
    float ai = sarea[base + i];
    int ci = scls[base + i];
    for (int j = jstart; j < jend; ++j) {
      float4 bj = sxyxy[base + j];
      float xx1 = fmaxf(bi.x, bj.x);
      float yy1 = fmaxf(bi.y, bj.y);
      float xx2 = fminf(bi.z, bj.z);
      float yy2 = fminf(bi.w, bj.w);
      float cw = fmaxf(xx2 - xx1 + 1.0f, 0.0f);
      float ch = fmaxf(yy2 - yy1 + 1.0f, 0.0f);
      float inter = __fmul_rn(cw, ch);               // block fp-contract
      float aj = sarea[base + j];
      float denom = (ai + aj) - inter;               // same assoc as reference
      float iou = inter / denom;
      if (iou >= NMS_THRV && scls[base + j] == ci) bits |= (1u << (j - j0));
    }
  }
  masksT[((size_t)b * 64 + w) * NN + i] = bits;
}

// ============ K3: chunked greedy scan (wave 0) + output write ==============
// 512-thread blocks => VGPR cap 256, so the 128-VGPR static pipeline cannot
// spill (round-3 lesson: dynamic indexing / VGPR pressure => scratch).
__global__ __launch_bounds__(512) void k_scan_write(
    const uint32_t* __restrict__ masksT,
    const int* __restrict__ nvalid,
    const float4* __restrict__ sxyxy,
    const float* __restrict__ sobj,
    const float* __restrict__ sconf,
    const int* __restrict__ scls,
    float* __restrict__ out) {
  __shared__ uint32_t rsh[64];
  int b = blockIdx.x;
  int t = threadIdx.x;

  if (t < 64) {
    int lane = t;
    const uint4* col = (const uint4*)(masksT + ((size_t)b * 64 + lane) * NN);
    uint32_t remv = 0;
    uint4 A[8], B[8], C[8], D[8];
#define LOADBUF(BUF, CH) do {                                          \
      _Pragma("unroll")                                                \
      for (int q = 0; q < 8; ++q) BUF[q] = col[(CH) * 8 + q];          \
    } while (0)
    LOADBUF(A, 0); LOADBUF(B, 1); LOADBUF(C, 2); LOADBUF(D, 3);
#define STEP(BUF, CH, RCH) do {                                        \
      uint32_t cur[32];                                                \
      _Pragma("unroll")                                                \
      for (int q = 0; q < 8; ++q) {                                    \
        cur[4*q+0] = BUF[q].x; cur[4*q+1] = BUF[q].y;                  \
        cur[4*q+2] = BUF[q].z; cur[4*q+3] = BUF[q].w;                  \
      }                                                                \
      { int rr = (RCH) < 64 ? (RCH) : 0; LOADBUF(BUF, rr); }           \
      uint32_t all_or = 0;                                             \
      _Pragma("unroll")                                                \
      for (int d = 0; d < 32; ++d) all_or |= cur[d];                   \
      uint32_t word_c = (uint32_t)__shfl((int)remv, (CH), 64);         \
      uint32_t diag   = (uint32_t)__shfl((int)all_or, (CH), 64);       \
      if (diag == 0u) {                                                \
        if (word_c == 0u) {                                            \
          remv |= all_or;                                              \
        } else {                                                       \
          uint32_t acc = 0;                                            \
          _Pragma("unroll")                                            \
          for (int d = 0; d < 32; ++d)                                 \
            acc |= ((word_c >> d) & 1u) ? 0u : cur[d];                 \
          remv |= acc;                                                 \
        }                                                              \
      } else {                                                         \
        uint32_t wc = word_c, acc = 0;                                 \
        _Pragma("unroll")                                              \
        for (int d = 0; d < 32; ++d) {                                 \
          uint32_t dd = (uint32_t)__shfl((int)cur[d], (CH), 64);       \
          if (((wc >> d) & 1u) == 0u) { wc |= dd; acc |= cur[d]; }     \
        }                                                              \
        remv |= acc;                                                   \
      }                                                                \
    } while (0)
    for (int c = 0; c < 64; c += 4) {
      STEP(A, c + 0, c + 4);
      STEP(B, c + 1, c + 5);
      STEP(C, c + 2, c + 6);
      STEP(D, c + 3, c + 7);
    }
#undef STEP
#undef LOADBUF
    rsh[lane] = remv;
  }
  __syncthreads();

  int nv = nvalid[b];
  #pragma unroll
  for (int rep = 0; rep < 4; ++rep) {
    int r = t + rep * 512;
    size_t idx = (size_t)b * NN + r;
    bool keep = false;
    if (r < nv) {
      uint32_t wrd = rsh[r >> 5];
      keep = !((wrd >> (r & 31)) & 1u);
    }
    float4 xy = make_float4(0.f, 0.f, 0.f, 0.f);
    float o = 0.f, cf = 0.f, cl = 0.f;
    if (keep) {
      xy = sxyxy[idx];
      o = sobj[idx];
      cf = sconf[idx];
      cl = (float)scls[idx];
    }
    float4* op = (float4*)(out + idx * 8);
    op[0] = make_float4((float)b, xy.x, xy.y, xy.z);
    op[1] = make_float4(xy.w, o, cf, cl);
  }
}

extern "C" void kernel_launch(void* const* d_in, const int* in_sizes, int n_in,
                              void* d_out, int out_size, void* d_ws, size_t ws_size,
                              hipStream_t stream) {
  const float4* boxes = (const float4*)d_in[0];        // [B][N][4]
  const float* obj = (const float*)d_in[1];            // [B][N]
  const float* logits = (const float*)d_in[2];         // [B][N][80]
  float* out = (float*)d_out;                          // [B][N][8]

  char* ws = (char*)d_ws;
  size_t off = 0;
  float4* sxyxy = (float4*)(ws + off);            off += (size_t)BB * NN * 16;
  float* sarea = (float*)(ws + off);              off += (size_t)BB * NN * 4;
  float* sobj = (float*)(ws + off);               off += (size_t)BB * NN * 4;
  float* sconf = (float*)(ws + off);              off += (size_t)BB * NN * 4;
  int* scls = (int*)(ws + off);                   off += (size_t)BB * NN * 4;
  int* nvalid = (int*)(ws + off);                 off += 256;
  uint32_t* masksT = (uint32_t*)(ws + off);       off += (size_t)BB * NN * 64 * 4;

  hipLaunchKernelGGL(k_sort_all, dim3(BB), dim3(512), 0, stream,
                     boxes, obj, logits,
                     sxyxy, sarea, sobj, sconf, scls, nvalid);
  hipLaunchKernelGGL(k_masks, dim3(NN * 64 / 256, BB), dim3(256), 0, stream,
                     sxyxy, sarea, scls, nvalid, masksT);
  hipLaunchKernelGGL(k_scan_write, dim3(BB), dim3(512), 0, stream,
                     masksT, nvalid, sxyxy, sobj, sconf, scls, out);
}

// Round 6
// 158.572 us; speedup vs baseline: 1.1698x; 1.1698x over previous
//
#include <hip/hip_runtime.h>
#include <stdint.h>

#define BB 16
#define NN 2048
#define CC 80
#define CONF_THRV 0.5f
#define NMS_THRV 0.5f

// ============ K0: class argmax/max + sort keys (FULL GRID) =================
// Round-5 lesson: this stage reads 10.5 MB of logits — it must stay spread
// across the whole GPU, never concentrated into per-batch blocks.
__global__ void k_classify(const float* __restrict__ logits,
                           const float* __restrict__ obj,
                           float* __restrict__ conf0,
                           int* __restrict__ cls0,
                           unsigned long long* __restrict__ keys) {
  int idx = blockIdx.x * blockDim.x + threadIdx.x;
  if (idx >= BB * NN) return;
  const float4* lp = (const float4*)(logits + (size_t)idx * CC);
  float best = -INFINITY;
  int bi = 0;
  #pragma unroll
  for (int q = 0; q < CC / 4; ++q) {
    float4 v = lp[q];
    if (v.x > best) { best = v.x; bi = 4 * q + 0; }
    if (v.y > best) { best = v.y; bi = 4 * q + 1; }
    if (v.z > best) { best = v.z; bi = 4 * q + 2; }
    if (v.w > best) { best = v.w; bi = 4 * q + 3; }
  }
  conf0[idx] = best;
  cls0[idx] = bi;
  float o = obj[idx];
  float s = (o > CONF_THRV) ? o : -INFINITY;
  unsigned u = __float_as_uint(s);
  u = (u & 0x80000000u) ? ~u : (u | 0x80000000u);
  unsigned n = (unsigned)(idx & (NN - 1));
  // descending key: score major, smaller original index first on ties.
  // All keys unique => rank-by-counting below is a permutation.
  keys[idx] = ((unsigned long long)u << 32) | (unsigned long long)(0xFFFFFFFFu - n);
}

// ============ K1: rank-by-counting + scatter (FULL GRID, replaces sort) ====
// rank[i] = #{j : key_j > key_i}. Unique keys => exact argsort(-score) order
// (stable: equal scores -> smaller idx -> larger key -> smaller rank).
// 2048^2 u64 compares per batch, embarrassingly parallel, zero barriers.
// nvalid = #{keys > flip(0.5) threshold key} falls out of the same loop.
__global__ __launch_bounds__(256) void k_rank_scatter(
    const float4* __restrict__ boxes,
    const float* __restrict__ obj,
    const unsigned long long* __restrict__ keys,
    const float* __restrict__ conf0,
    const int* __restrict__ cls0,
    float4* __restrict__ sxyxy,
    float* __restrict__ sarea,
    float* __restrict__ sobj,
    float* __restrict__ sconf,
    int* __restrict__ scls,
    int* __restrict__ nvalid) {
  __shared__ unsigned long long lk[NN];     // 16 KB: whole batch's keys
  int b = blockIdx.y;
  int t = threadIdx.x;
  size_t base = (size_t)b * NN;
  #pragma unroll
  for (int r = 0; r < NN / 256; ++r)
    lk[t + r * 256] = keys[base + t + r * 256];
  __syncthreads();

  int i = blockIdx.x * 256 + t;
  unsigned long long ki = lk[i];
  // valid  <=>  obj > 0.5  <=>  key > (flip(0.5)<<32 | 0xFFFFFFFF)
  const unsigned long long VK = (0xBF000000ull << 32) | 0xFFFFFFFFull;
  int rank = 0, vcnt = 0;
  const ulonglong2* lk2 = (const ulonglong2*)lk;
  #pragma unroll 4
  for (int j = 0; j < NN / 2; j += 2) {     // broadcast LDS reads, b128 pairs
    ulonglong2 a = lk2[j];
    ulonglong2 c = lk2[j + 1];
    rank += (a.x > ki) + (a.y > ki) + (c.x > ki) + (c.y > ki);
    vcnt += (a.x > VK) + (a.y > VK) + (c.x > VK) + (c.y > VK);
  }
  if (t == 0) nvalid[b] = vcnt;             // redundant same-value writes, ok

  // scatter anchor i's transformed data to its sorted position
  float4 bx = boxes[base + i];
  float hw = bx.z / 2.0f, hh = bx.w / 2.0f;
  float x1 = bx.x - hw, y1 = bx.y - hh;
  float x2 = bx.x + hw, y2 = bx.y + hh;
  sxyxy[base + rank] = make_float4(x1, y1, x2, y2);
  sarea[base + rank] = __fmul_rn(x2 - x1 + 1.0f, y2 - y1 + 1.0f);
  sobj[base + rank] = obj[base + i];
  sconf[base + rank] = conf0[base + i];
  scls[base + rank] = cls0[base + i];
}

// ============ K2: suppression masks, TRANSPOSED layout (unchanged) =========
// masksT[(b*64 + w)*NN + i] = bits for rows j in [32w,32w+32) suppressed by i.
// All i<2048 rows written (zeros where inactive) so the scan needs no guards.
__global__ void k_masks(const float4* __restrict__ sxyxy,
                        const float* __restrict__ sarea,
                        const int* __restrict__ scls,
                        const int* __restrict__ nvalid,
                        uint32_t* __restrict__ masksT) {
  int b = blockIdx.y;
  int pair = blockIdx.x * blockDim.x + threadIdx.x;  // [0, NN*64)
  int i = pair & (NN - 1);
  int w = pair >> 11;
  int nv = nvalid[b];
  size_t base = (size_t)b * NN;
  uint32_t bits = 0;
  int j0 = w * 32;
  int jend = min(j0 + 32, nv);
  int jstart = max(j0, i + 1);
  if (i < nv && jstart < jend) {
    float4 bi = sxyxy[base + i];
    float ai = sarea[base + i];
    int ci = scls[base + i];
    for (int j = jstart; j < jend; ++j) {
      float4 bj = sxyxy[base + j];
      float xx1 = fmaxf(bi.x, bj.x);
      float yy1 = fmaxf(bi.y, bj.y);
      float xx2 = fminf(bi.z, bj.z);
      float yy2 = fminf(bi.w, bj.w);
      float cw = fmaxf(xx2 - xx1 + 1.0f, 0.0f);
      float ch = fmaxf(yy2 - yy1 + 1.0f, 0.0f);
      float inter = __fmul_rn(cw, ch);               // block fp-contract
      float aj = sarea[base + j];
      float denom = (ai + aj) - inter;               // same assoc as reference
      float iou = inter / denom;
      if (iou >= NMS_THRV && scls[base + j] == ci) bits |= (1u << (j - j0));
    }
  }
  masksT[((size_t)b * 64 + w) * NN + i] = bits;
}

// ============ K3: chunked greedy scan (wave 0) + output write (unchanged) ==
__global__ __launch_bounds__(512) void k_scan_write(
    const uint32_t* __restrict__ masksT,
    const int* __restrict__ nvalid,
    const float4* __restrict__ sxyxy,
    const float* __restrict__ sobj,
    const float* __restrict__ sconf,
    const int* __restrict__ scls,
    float* __restrict__ out) {
  __shared__ uint32_t rsh[64];
  int b = blockIdx.x;
  int t = threadIdx.x;

  if (t < 64) {
    int lane = t;
    const uint4* col = (const uint4*)(masksT + ((size_t)b * 64 + lane) * NN);
    uint32_t remv = 0;
    uint4 A[8], B[8], C[8], D[8];
#define LOADBUF(BUF, CH) do {                                          \
      _Pragma("unroll")                                                \
      for (int q = 0; q < 8; ++q) BUF[q] = col[(CH) * 8 + q];          \
    } while (0)
    LOADBUF(A, 0); LOADBUF(B, 1); LOADBUF(C, 2); LOADBUF(D, 3);
#define STEP(BUF, CH, RCH) do {                                        \
      uint32_t cur[32];                                                \
      _Pragma("unroll")                                                \
      for (int q = 0; q < 8; ++q) {                                    \
        cur[4*q+0] = BUF[q].x; cur[4*q+1] = BUF[q].y;                  \
        cur[4*q+2] = BUF[q].z; cur[4*q+3] = BUF[q].w;                  \
      }                                                                \
      { int rr = (RCH) < 64 ? (RCH) : 0; LOADBUF(BUF, rr); }           \
      uint32_t all_or = 0;                                             \
      _Pragma("unroll")                                                \
      for (int d = 0; d < 32; ++d) all_or |= cur[d];                   \
      uint32_t word_c = (uint32_t)__shfl((int)remv, (CH), 64);         \
      uint32_t diag   = (uint32_t)__shfl((int)all_or, (CH), 64);       \
      if (diag == 0u) {                                                \
        if (word_c == 0u) {                                            \
          remv |= all_or;                                              \
        } else {                                                       \
          uint32_t acc = 0;                                            \
          _Pragma("unroll")                                            \
          for (int d = 0; d < 32; ++d)                                 \
            acc |= ((word_c >> d) & 1u) ? 0u : cur[d];                 \
          remv |= acc;                                                 \
        }                                                              \
      } else {                                                         \
        uint32_t wc = word_c, acc = 0;                                 \
        _Pragma("unroll")                                              \
        for (int d = 0; d < 32; ++d) {                                 \
          uint32_t dd = (uint32_t)__shfl((int)cur[d], (CH), 64);       \
          if (((wc >> d) & 1u) == 0u) { wc |= dd; acc |= cur[d]; }     \
        }                                                              \
        remv |= acc;                                                   \
      }                                                                \
    } while (0)
    for (int c = 0; c < 64; c += 4) {
      STEP(A, c + 0, c + 4);
      STEP(B, c + 1, c + 5);
      STEP(C, c + 2, c + 6);
      STEP(D, c + 3, c + 7);
    }
#undef STEP
#undef LOADBUF
    rsh[lane] = remv;
  }
  __syncthreads();

  int nv = nvalid[b];
  #pragma unroll
  for (int rep = 0; rep < 4; ++rep) {
    int r = t + rep * 512;
    size_t idx = (size_t)b * NN + r;
    bool keep = false;
    if (r < nv) {
      uint32_t wrd = rsh[r >> 5];
      keep = !((wrd >> (r & 31)) & 1u);
    }
    float4 xy = make_float4(0.f, 0.f, 0.f, 0.f);
    float o = 0.f, cf = 0.f, cl = 0.f;
    if (keep) {
      xy = sxyxy[idx];
      o = sobj[idx];
      cf = sconf[idx];
      cl = (float)scls[idx];
    }
    float4* op = (float4*)(out + idx * 8);
    op[0] = make_float4((float)b, xy.x, xy.y, xy.z);
    op[1] = make_float4(xy.w, o, cf, cl);
  }
}

extern "C" void kernel_launch(void* const* d_in, const int* in_sizes, int n_in,
                              void* d_out, int out_size, void* d_ws, size_t ws_size,
                              hipStream_t stream) {
  const float4* boxes = (const float4*)d_in[0];        // [B][N][4]
  const float* obj = (const float*)d_in[1];            // [B][N]
  const float* logits = (const float*)d_in[2];         // [B][N][80]
  float* out = (float*)d_out;                          // [B][N][8]

  char* ws = (char*)d_ws;
  size_t off = 0;
  float4* sxyxy = (float4*)(ws + off);            off += (size_t)BB * NN * 16;
  unsigned long long* keys = (unsigned long long*)(ws + off); off += (size_t)BB * NN * 8;
  float* conf0 = (float*)(ws + off);              off += (size_t)BB * NN * 4;
  int* cls0 = (int*)(ws + off);                   off += (size_t)BB * NN * 4;
  float* sarea = (float*)(ws + off);              off += (size_t)BB * NN * 4;
  float* sobj = (float*)(ws + off);               off += (size_t)BB * NN * 4;
  float* sconf = (float*)(ws + off);              off += (size_t)BB * NN * 4;
  int* scls = (int*)(ws + off);                   off += (size_t)BB * NN * 4;
  int* nvalid = (int*)(ws + off);                 off += 256;
  uint32_t* masksT = (uint32_t*)(ws + off);       off += (size_t)BB * NN * 64 * 4;

  hipLaunchKernelGGL(k_classify, dim3((BB * NN + 255) / 256), dim3(256), 0, stream,
                     logits, obj, conf0, cls0, keys);
  hipLaunchKernelGGL(k_rank_scatter, dim3(NN / 256, BB), dim3(256), 0, stream,
                     boxes, obj, keys, conf0, cls0,
                     sxyxy, sarea, sobj, sconf, scls, nvalid);
  hipLaunchKernelGGL(k_masks, dim3(NN * 64 / 256, BB), dim3(256), 0, stream,
                     sxyxy, sarea, scls, nvalid, masksT);
  hipLaunchKernelGGL(k_scan_write, dim3(BB), dim3(512), 0, stream,
                     masksT, nvalid, sxyxy, sobj, sconf, scls, out);
}

// Round 7
// 147.710 us; speedup vs baseline: 1.2558x; 1.0735x over previous
//
#include <hip/hip_runtime.h>
#include <stdint.h>

#define BB 16
#define NN 2048
#define CC 80
#define CONF_THRV 0.5f
#define NMS_THRV 0.5f

// ============ K1: keys + rank-by-counting + own-anchor classify + scatter ==
// Grid (NN/256, BB) = 128 blocks. Keys depend only on obj, so every block
// rebuilds the whole batch's keys from an 8 KB obj read (L2-resident).
// rank[i] = #{j : key_j > key_i}; unique keys => exact stable argsort(-score).
// Invalid anchors (obj<=0.5) have rank >= nv, and slots >= nv are never read
// downstream => skip their rank loop, logits argmax, and scatter entirely.
__global__ __launch_bounds__(256) void k_rank_all(
    const float4* __restrict__ boxes,
    const float* __restrict__ obj,
    const float* __restrict__ logits,
    float4* __restrict__ sxyxy,
    float* __restrict__ sarea,
    float* __restrict__ sobj,
    float* __restrict__ sconf,
    int* __restrict__ scls,
    int* __restrict__ nvalid) {
  __shared__ unsigned long long lk[NN];   // 16 KB
  __shared__ int cnt;
  int b = blockIdx.y;
  int t = threadIdx.x;
  if (t == 0) cnt = 0;
  __syncthreads();
  size_t base = (size_t)b * NN;
  int myv = 0;
  #pragma unroll
  for (int r = 0; r < NN / 256; ++r) {
    int a = t + r * 256;
    float o = obj[base + a];
    bool v = o > CONF_THRV;
    float s = v ? o : -INFINITY;
    unsigned u = __float_as_uint(s);
    u = (u & 0x80000000u) ? ~u : (u | 0x80000000u);
    // descending key: score major, smaller original index first on ties
    lk[a] = ((unsigned long long)u << 32) |
            (unsigned long long)(0xFFFFFFFFu - (unsigned)a);
    myv += v ? 1 : 0;
  }
  atomicAdd(&cnt, myv);
  __syncthreads();
  if (t == 0) nvalid[b] = cnt;            // 8 blocks/batch write same value

  int i = blockIdx.x * 256 + t;
  unsigned long long ki = lk[i];
  // valid <=> obj>0.5 <=> key > (flip(0.5f)<<32 | 0xFFFFFFFF)
  const unsigned long long VK = (0xBF000000ull << 32) | 0xFFFFFFFFull;
  if (ki <= VK) return;                   // slot rank>=nv is never read

  int rank = 0;
  const ulonglong2* lk2 = (const ulonglong2*)lk;
  #pragma unroll 4
  for (int j = 0; j < NN / 2; j += 2) {   // broadcast LDS reads, b128 pairs
    ulonglong2 a2 = lk2[j];
    ulonglong2 c2 = lk2[j + 1];
    rank += (a2.x > ki) + (a2.y > ki) + (c2.x > ki) + (c2.y > ki);
  }

  // class argmax for own (valid) anchor only — ~half the logits traffic
  const float4* lp = (const float4*)(logits + (base + i) * CC);
  float best = -INFINITY;
  int bi = 0;
  #pragma unroll
  for (int q = 0; q < CC / 4; ++q) {
    float4 v4 = lp[q];
    if (v4.x > best) { best = v4.x; bi = 4 * q + 0; }
    if (v4.y > best) { best = v4.y; bi = 4 * q + 1; }
    if (v4.z > best) { best = v4.z; bi = 4 * q + 2; }
    if (v4.w > best) { best = v4.w; bi = 4 * q + 3; }
  }

  float4 bx = boxes[base + i];
  float hw = bx.z / 2.0f, hh = bx.w / 2.0f;
  float x1 = bx.x - hw, y1 = bx.y - hh;
  float x2 = bx.x + hw, y2 = bx.y + hh;
  sxyxy[base + rank] = make_float4(x1, y1, x2, y2);
  sarea[base + rank] = __fmul_rn(x2 - x1 + 1.0f, y2 - y1 + 1.0f);
  sobj[base + rank] = obj[base + i];
  sconf[base + rank] = best;
  scls[base + rank] = bi;
}

// ============ K2: suppression masks, transposed, only live words ===========
// masksT[(b*64 + w)*NN + i] = bits for rows j in [32w,32w+32) suppressed by i.
// Only words w < nwords=ceil(nv/32) are stored (i in [0,2048) all written,
// zeros where dead, so the scan's rounded-up chunks OR in zeros harmlessly).
__global__ void k_masks(const float4* __restrict__ sxyxy,
                        const float* __restrict__ sarea,
                        const int* __restrict__ scls,
                        const int* __restrict__ nvalid,
                        uint32_t* __restrict__ masksT) {
  int b = blockIdx.y;
  int pair = blockIdx.x * blockDim.x + threadIdx.x;  // [0, NN*64)
  int i = pair & (NN - 1);
  int w = pair >> 11;
  int nv = nvalid[b];
  int nwords = (nv + 31) >> 5;
  if (w >= nwords) return;              // scan never reads these words
  size_t base = (size_t)b * NN;
  uint32_t bits = 0;
  int j0 = w * 32;
  int jend = min(j0 + 32, nv);
  int jstart = max(j0, i + 1);
  if (i < nv && jstart < jend) {
    float4 bi = sxyxy[base + i];
    float ai = sarea[base + i];
    int ci = scls[base + i];
    for (int j = jstart; j < jend; ++j) {
      float4 bj = sxyxy[base + j];
      float xx1 = fmaxf(bi.x, bj.x);
      float yy1 = fmaxf(bi.y, bj.y);
      float xx2 = fminf(bi.z, bj.z);
      float yy2 = fminf(bi.w, bj.w);
      float cw = fmaxf(xx2 - xx1 + 1.0f, 0.0f);
      float ch = fmaxf(yy2 - yy1 + 1.0f, 0.0f);
      float inter = __fmul_rn(cw, ch);               // block fp-contract
      float aj = sarea[base + j];
      float denom = (ai + aj) - inter;               // same assoc as reference
      float iou = inter / denom;
      if (iou >= NMS_THRV && scls[base + j] == ci) bits |= (1u << (j - j0));
    }
  }
  masksT[((size_t)b * 64 + w) * NN + i] = bits;
}

// ============ K3: chunked greedy scan (wave 0) + output write ==============
// Dynamic chunk count nch4 = ceil(nch/4)*4; lanes >= nwords are
// load-predicated to zero (their words were never stored). Static named
// buffers only — round-3 lesson: dynamic register indexing => scratch.
__global__ __launch_bounds__(512) void k_scan_write(
    const uint32_t* __restrict__ masksT,
    const int* __restrict__ nvalid,
    const float4* __restrict__ sxyxy,
    const float* __restrict__ sobj,
    const float* __restrict__ sconf,
    const int* __restrict__ scls,
    float* __restrict__ out) {
  __shared__ uint32_t rsh[64];
  int b = blockIdx.x;
  int t = threadIdx.x;
  int nv = nvalid[b];

  if (t < 64) {
    int lane = t;
    int nwords = (nv + 31) >> 5;
    int nch4 = (nwords + 3) & ~3;       // chunks, rounded to pipeline depth
    bool act = lane < nwords;
    const uint4* col = (const uint4*)(masksT + ((size_t)b * 64 + lane) * NN);
    uint32_t remv = 0;
    uint4 z4; z4.x = z4.y = z4.z = z4.w = 0u;
    uint4 A[8], B[8], C[8], D[8];
    #pragma unroll
    for (int q = 0; q < 8; ++q) { A[q] = z4; B[q] = z4; C[q] = z4; D[q] = z4; }
#define LOADBUF(BUF, CH) do {                                          \
      if (act) {                                                       \
        int rr = (CH) < 64 ? (CH) : 0;                                 \
        _Pragma("unroll")                                              \
        for (int q = 0; q < 8; ++q) BUF[q] = col[rr * 8 + q];          \
      }                                                                \
    } while (0)
    LOADBUF(A, 0); LOADBUF(B, 1); LOADBUF(C, 2); LOADBUF(D, 3);
#define STEP(BUF, CH, RCH) do {                                        \
      uint32_t cur[32];                                                \
      _Pragma("unroll")                                                \
      for (int q = 0; q < 8; ++q) {                                    \
        cur[4*q+0] = BUF[q].x; cur[4*q+1] = BUF[q].y;                  \
        cur[4*q+2] = BUF[q].z; cur[4*q+3] = BUF[q].w;                  \
      }                                                                \
      LOADBUF(BUF, RCH);                                               \
      uint32_t all_or = 0;                                             \
      _Pragma("unroll")                                                \
      for (int d = 0; d < 32; ++d) all_or |= cur[d];                   \
      uint32_t word_c = (uint32_t)__shfl((int)remv, (CH), 64);         \
      uint32_t diag   = (uint32_t)__shfl((int)all_or, (CH), 64);       \
      if (diag == 0u) {                                                \
        if (word_c == 0u) {                                            \
          remv |= all_or;                                              \
        } else {                                                       \
          uint32_t acc = 0;                                            \
          _Pragma("unroll")                                            \
          for (int d = 0; d < 32; ++d)                                 \
            acc |= ((word_c >> d) & 1u) ? 0u : cur[d];                 \
          remv |= acc;                                                 \
        }                                                              \
      } else {                                                         \
        uint32_t wc = word_c, acc = 0;                                 \
        _Pragma("unroll")                                              \
        for (int d = 0; d < 32; ++d) {                                 \
          uint32_t dd = (uint32_t)__shfl((int)cur[d], (CH), 64);       \
          if (((wc >> d) & 1u) == 0u) { wc |= dd; acc |= cur[d]; }     \
        }                                                              \
        remv |= acc;                                                   \
      }                                                                \
    } while (0)
    for (int c = 0; c < nch4; c += 4) {
      STEP(A, c + 0, c + 4);
      STEP(B, c + 1, c + 5);
      STEP(C, c + 2, c + 6);
      STEP(D, c + 3, c + 7);
    }
#undef STEP
#undef LOADBUF
    rsh[lane] = remv;
  }
  __syncthreads();

  #pragma unroll
  for (int rep = 0; rep < 4; ++rep) {
    int r = t + rep * 512;
    size_t idx = (size_t)b * NN + r;
    bool keep = false;
    if (r < nv) {
      uint32_t wrd = rsh[r >> 5];
      keep = !((wrd >> (r & 31)) & 1u);
    }
    float4 xy = make_float4(0.f, 0.f, 0.f, 0.f);
    float o = 0.f, cf = 0.f, cl = 0.f;
    if (keep) {
      xy = sxyxy[idx];
      o = sobj[idx];
      cf = sconf[idx];
      cl = (float)scls[idx];
    }
    float4* op = (float4*)(out + idx * 8);
    op[0] = make_float4((float)b, xy.x, xy.y, xy.z);
    op[1] = make_float4(xy.w, o, cf, cl);
  }
}

extern "C" void kernel_launch(void* const* d_in, const int* in_sizes, int n_in,
                              void* d_out, int out_size, void* d_ws, size_t ws_size,
                              hipStream_t stream) {
  const float4* boxes = (const float4*)d_in[0];        // [B][N][4]
  const float* obj = (const float*)d_in[1];            // [B][N]
  const float* logits = (const float*)d_in[2];         // [B][N][80]
  float* out = (float*)d_out;                          // [B][N][8]

  char* ws = (char*)d_ws;
  size_t off = 0;
  float4* sxyxy = (float4*)(ws + off);            off += (size_t)BB * NN * 16;
  float* sarea = (float*)(ws + off);              off += (size_t)BB * NN * 4;
  float* sobj = (float*)(ws + off);               off += (size_t)BB * NN * 4;
  float* sconf = (float*)(ws + off);              off += (size_t)BB * NN * 4;
  int* scls = (int*)(ws + off);                   off += (size_t)BB * NN * 4;
  int* nvalid = (int*)(ws + off);                 off += 256;
  uint32_t* masksT = (uint32_t*)(ws + off);       off += (size_t)BB * NN * 64 * 4;

  hipLaunchKernelGGL(k_rank_all, dim3(NN / 256, BB), dim3(256), 0, stream,
                     boxes, obj, logits,
                     sxyxy, sarea, sobj, sconf, scls, nvalid);
  hipLaunchKernelGGL(k_masks, dim3(NN * 64 / 256, BB), dim3(256), 0, stream,
                     sxyxy, sarea, scls, nvalid, masksT);
  hipLaunchKernelGGL(k_scan_write, dim3(BB), dim3(512), 0, stream,
                     masksT, nvalid, sxyxy, sobj, sconf, scls, out);
}